// Round 4
// baseline (430.827 us; speedup 1.0000x reference)
//
#include <hip/hip_runtime.h>

typedef __attribute__((ext_vector_type(8))) short bf16x8;
typedef __attribute__((ext_vector_type(4))) float f32x4;

__device__ __forceinline__ unsigned short f2bf(float f) {
    union { float f; unsigned int u; } v; v.f = f;
    unsigned int u = v.u;
    return (unsigned short)((u + 0x7FFFu + ((u >> 16) & 1u)) >> 16);
}

__device__ __forceinline__ void cp16_g2l(const void* g, void* l) {
    __builtin_amdgcn_global_load_lds(
        (const __attribute__((address_space(1))) unsigned int*)g,
        (__attribute__((address_space(3))) unsigned int*)l, 16, 0, 0);
}

// ---- one-time: W_h f32 [128][384] -> plain bf16 row-major image in ws ----
__global__ __launch_bounds__(384) void k_cvtW(const float* __restrict__ Wh,
                                              unsigned short* __restrict__ Wbf) {
    int n = blockIdx.x, k = threadIdx.x;
    Wbf[n * 384 + k] = f2bf(Wh[n * 384 + k]);
}

// ---------------- level kernel ----------------
// Block tile: 64 own rows x 128 cols. 4 waves, wave = all 64 rows x 32 cols (wc=wid).
// W in registers: each wave holds its 32-col quarter (24 bf16x8 = 96 VGPR).
// emb child-image layout, keyed to 64-own-row consumer tiles (128 child rows):
//   child row R: tc=R>>7, rr=R&127, cc=rr&1, il=rr>>1
//   elem offset = tc*16384 + (cc*64+il)*128 + (n ^ ((il&7)<<3))
// -> consumer A-stage is a linear 32 KiB DMA; producer epilogue is linear too.
template<int LEAF, int LAST>
__global__ __launch_bounds__(256, 3) void k_level(
    const unsigned short* __restrict__ embIn,
    const float* __restrict__ contO,   // [n][8] own contents
    const float* __restrict__ contC,   // [2n][8] child contents (LEAF only)
    const unsigned short* __restrict__ Wbf, // plain bf16 W image [128*384]
    const float* __restrict__ Wu,      // [128][8]
    const float* __restrict__ bu,      // [128]
    const float* __restrict__ bh,      // [128]
    unsigned short* __restrict__ embOut, // child-image layout
    float* __restrict__ outF,          // row-major f32 (LAST)
    int n_nodes)
{
    // LDS: 32K (A) + 16K (u) + 1K + 2K = 51 KiB -> 3 blocks/CU
    __shared__ __align__(16) unsigned short A_lds[2][64][128]; // [cc][il][n^swz]
    __shared__ __align__(16) unsigned short u_lds[64][128];    // [i][n^swz]
    __shared__ __align__(16) unsigned short cpO[64][8];
    __shared__ __align__(16) unsigned short cpC[128][8];

    int t = threadIdx.x, lane = t & 63, wid = t >> 6;   // 4 waves, wid = col quarter
    int l15 = lane & 15, l4 = lane >> 4;

    // ---- persistent W fragments: n = wid*32 + nf2*16 + l15, k = kb*32 + l4*8 + e ----
    bf16x8 wreg[2][12];
    #pragma unroll
    for (int nf2 = 0; nf2 < 2; ++nf2) {
        int n = wid * 32 + nf2 * 16 + l15;
        #pragma unroll
        for (int kb = 0; kb < 12; ++kb)
            wreg[nf2][kb] = *reinterpret_cast<const bf16x8*>(Wbf + n * 384 + kb * 32 + l4 * 8);
    }

    // ---- register Wu/bu fragments (B-op of the K=32-padded u-GEMM) ----
    bf16x8 wuf[8];
    #pragma unroll
    for (int nf = 0; nf < 8; ++nf) {
        bf16x8 v = {0, 0, 0, 0, 0, 0, 0, 0};
        int n = nf * 16 + l15;
        if (l4 == 0) {
            #pragma unroll
            for (int k = 0; k < 8; ++k) ((unsigned short*)&v)[k] = f2bf(Wu[n * 8 + k]);
        } else if (l4 == 1) {
            ((unsigned short*)&v)[0] = f2bf(bu[n]);   // bias column (k=8)
        }
        wuf[nf] = v;
    }
    float bhv[2];
    #pragma unroll
    for (int nf2 = 0; nf2 < 2; ++nf2) bhv[nf2] = bh[wid * 32 + nf2 * 16 + l15];

    bf16x8 onesA = {0, 0, 0, 0, 0, 0, 0, 0};
    ((unsigned short*)&onesA)[0] = 0x3F80;            // 1.0 at k=8
    const bf16x8 zeroA = {0, 0, 0, 0, 0, 0, 0, 0};

    int ntiles = n_nodes >> 6;
    for (int tile = blockIdx.x; tile < ntiles; tile += gridDim.x) {
        __syncthreads();  // (1) prev tile fully done (incl. epilogue LDS reads)

        if (!LEAF) {
            // A image: 2048 x 16B contiguous chunks, linear DMA (32 KiB)
            const unsigned short* src = embIn + (size_t)tile * 16384;
            #pragma unroll
            for (int it = 0; it < 8; ++it) {
                int q = t + it * 256;
                cp16_g2l(src + q * 8, &A_lds[0][0][0] + q * 8);
            }
        } else {
            // child contents: 128 rows x 8
            #pragma unroll
            for (int it = 0; it < 4; ++it) {
                int e = t + it * 256;
                cpC[e >> 3][e & 7] = f2bf(contC[(size_t)tile * 1024 + e]);
            }
        }
        // own contents: 64 rows x 8
        #pragma unroll
        for (int it = 0; it < 2; ++it) {
            int e = t + it * 256;
            cpO[e >> 3][e & 7] = f2bf(contO[(size_t)tile * 512 + e]);
        }

        // (2) barrier draining LDS writes but NOT the A DMA (vmcnt) -> DMA overlaps u-phase
        asm volatile("s_waitcnt lgkmcnt(0)" ::: "memory");
        __builtin_amdgcn_s_barrier();
        __builtin_amdgcn_sched_barrier(0);

        if (LEAF) {
            // child-u: wave computes child rows wid*32..+31, all 128 cols, into A image
            #pragma unroll
            for (int rb = 0; rb < 2; ++rb) {
                bf16x8 ac = (l4 == 0) ? *(const bf16x8*)&cpC[wid * 32 + rb * 16 + l15][0]
                          : (l4 == 1) ? onesA : zeroA;
                #pragma unroll
                for (int nf = 0; nf < 8; ++nf) {
                    f32x4 z = {0.f, 0.f, 0.f, 0.f};
                    z = __builtin_amdgcn_mfma_f32_16x16x32_bf16(ac, wuf[nf], z, 0, 0, 0);
                    #pragma unroll
                    for (int r = 0; r < 4; ++r) {
                        int rr = wid * 32 + rb * 16 + l4 * 4 + r;  // local child row
                        int cc = rr & 1, il = rr >> 1;
                        int n = nf * 16 + l15;
                        A_lds[cc][il][n ^ ((il & 7) << 3)] = f2bf(fmaxf(z[r], 0.f));
                    }
                }
            }
        }
        {
            // own-u: wave rows wid*16..+15, all 128 cols
            bf16x8 au = (l4 == 0) ? *(const bf16x8*)&cpO[wid * 16 + l15][0]
                      : (l4 == 1) ? onesA : zeroA;
            #pragma unroll
            for (int nf = 0; nf < 8; ++nf) {
                f32x4 z = {0.f, 0.f, 0.f, 0.f};
                z = __builtin_amdgcn_mfma_f32_16x16x32_bf16(au, wuf[nf], z, 0, 0, 0);
                #pragma unroll
                for (int r = 0; r < 4; ++r) {
                    int iu = wid * 16 + l4 * 4 + r;
                    int n = nf * 16 + l15;
                    u_lds[iu][n ^ ((iu & 7) << 3)] = f2bf(fmaxf(z[r], 0.f));
                }
            }
        }
        __syncthreads();  // (3) drains A DMA (vmcnt) + u/A LDS writes

        // ---- main GEMM: K=384 = [child0 | child1 | u], B entirely from registers ----
        f32x4 acc[4][2];
        #pragma unroll
        for (int mf = 0; mf < 4; ++mf)
            #pragma unroll
            for (int nf2 = 0; nf2 < 2; ++nf2)
                acc[mf][nf2] = (f32x4){bhv[nf2], bhv[nf2], bhv[nf2], bhv[nf2]};

        #pragma unroll
        for (int kb = 0; kb < 12; ++kb) {
            bf16x8 af[4];
            #pragma unroll
            for (int mf = 0; mf < 4; ++mf) {
                int i = mf * 16 + l15;
                const unsigned short* ap;
                if (kb < 8) ap = &A_lds[kb >> 2][i][((((kb & 3) * 4) + l4) ^ (i & 7)) * 8];
                else        ap = &u_lds[i][((((kb - 8) * 4) + l4) ^ (i & 7)) * 8];
                af[mf] = *(const bf16x8*)ap;
            }
            #pragma unroll
            for (int mf = 0; mf < 4; ++mf)
                #pragma unroll
                for (int nf2 = 0; nf2 < 2; ++nf2)
                    acc[mf][nf2] = __builtin_amdgcn_mfma_f32_16x16x32_bf16(af[mf], wreg[nf2][kb], acc[mf][nf2], 0, 0, 0);
        }

        // ---- epilogue ----
        if (LAST) {
            #pragma unroll
            for (int mf = 0; mf < 4; ++mf)
                #pragma unroll
                for (int nf2 = 0; nf2 < 2; ++nf2)
                    #pragma unroll
                    for (int r = 0; r < 4; ++r) {
                        int i = mf * 16 + l4 * 4 + r;
                        int n = wid * 32 + nf2 * 16 + l15;
                        outF[(size_t)(tile * 64 + i) * 128 + n] = fmaxf(acc[mf][nf2][r], 0.f);
                    }
        } else {
            // bounce through (dead) A_lds in image layout, then coalesced 16B stores
            __syncthreads();  // (4) all A/u reads done -> A_lds reusable
            unsigned short* ep = &A_lds[0][0][0];
            #pragma unroll
            for (int mf = 0; mf < 4; ++mf)
                #pragma unroll
                for (int nf2 = 0; nf2 < 2; ++nf2)
                    #pragma unroll
                    for (int r = 0; r < 4; ++r) {
                        int i = mf * 16 + l4 * 4 + r;
                        int n = wid * 32 + nf2 * 16 + l15;
                        // image pos for produced row Rg=tile*64+i: cc=i&1, il'=i>>1
                        int row = (i & 1) * 32 + (i >> 1);
                        ep[row * 128 + (n ^ (((i >> 1) & 7) << 3))] = f2bf(fmaxf(acc[mf][nf2][r], 0.f));
                    }
            __syncthreads();  // (5) ep writes visible
            size_t gbase = (size_t)(tile >> 1) * 16384 + (size_t)(tile & 1) * 4096;
            #pragma unroll
            for (int c = 0; c < 4; ++c) {
                int q = c * 256 + t;  // 16B chunk id, 1024 total
                bf16x8 v = *(const bf16x8*)&ep[q * 8];
                *reinterpret_cast<bf16x8*>(embOut + gbase + (size_t)(q >> 9) * 8192 + (q & 511) * 8) = v;
            }
        }
    }
}

extern "C" void kernel_launch(void* const* d_in, const int* in_sizes, int n_in,
                              void* d_out, int out_size, void* d_ws, size_t ws_size,
                              hipStream_t stream) {
    const float* contents[10];
    for (int j = 0; j < 10; ++j) contents[j] = (const float*)d_in[j];
    const float* Wu = (const float*)d_in[19];
    const float* bu = (const float*)d_in[20];
    const float* Wh = (const float*)d_in[21];
    const float* bh = (const float*)d_in[22];

    unsigned short* Wbf  = (unsigned short*)d_ws;                                     // 96 KiB
    unsigned short* bufE = (unsigned short*)((char*)d_ws + (1u << 20));               // 64 MiB (even-level embs)
    unsigned short* bufO = (unsigned short*)((char*)d_ws + (1u << 20) + (64u << 20)); // 32 MiB (odd-level embs)

    k_cvtW<<<128, 384, 0, stream>>>(Wh, Wbf);

    // level 8 (leaf-fused): children = relu(contents_9 @ Wu^T + bu) computed in-kernel
    {
        int ntiles = (1024 << 8) >> 6;   // 4096
        int grid = ntiles < 768 ? ntiles : 768;
        k_level<1, 0><<<grid, 256, 0, stream>>>(nullptr, contents[8], contents[9], Wbf,
                                                Wu, bu, bh, bufE, nullptr, 1024 << 8);
    }
    // levels 7..1
    for (int j = 7; j >= 1; --j) {
        int n = 1024 << j;
        const unsigned short* in = (j & 1) ? bufE : bufO;  // emb_{j+1}
        unsigned short* outp     = (j & 1) ? bufO : bufE;  // emb_j
        int ntiles = n >> 6;
        int grid = ntiles < 768 ? ntiles : 768;
        k_level<0, 0><<<grid, 256, 0, stream>>>(in, contents[j], nullptr, Wbf,
                                                Wu, bu, bh, outp, nullptr, n);
    }
    // level 0 -> f32 output (16 tiles)
    k_level<0, 1><<<16, 256, 0, stream>>>(bufO, contents[0], nullptr, Wbf,
                                          Wu, bu, bh, nullptr, (float*)d_out, 1024);
}

// Round 5
// 253.732 us; speedup vs baseline: 1.6980x; 1.6980x over previous
//
#include <hip/hip_runtime.h>

typedef __attribute__((ext_vector_type(8))) short bf16x8;
typedef __attribute__((ext_vector_type(4))) float f32x4;

__device__ __forceinline__ unsigned short f2bf(float f) {
    union { float f; unsigned int u; } v; v.f = f;
    unsigned int u = v.u;
    return (unsigned short)((u + 0x7FFFu + ((u >> 16) & 1u)) >> 16);
}

__device__ __forceinline__ void cp16_g2l(const void* g, void* l) {
    __builtin_amdgcn_global_load_lds(
        (const __attribute__((address_space(1))) unsigned int*)g,
        (__attribute__((address_space(3))) unsigned int*)l, 16, 0, 0);
}

// ---------------- level kernel ----------------
// Block tile: 64 own rows x 128 cols. 4 waves, wave = all 64 rows x 32 cols (wc=wid).
// W in registers (loaded from f32 once, pinned vs rematerialization).
// emb child-image layout, keyed to 64-own-row consumer tiles (128 child rows):
//   child row R: tc=R>>7, rr=R&127, cc=rr&1, il=rr>>1
//   elem offset = tc*16384 + (cc*64+il)*128 + (n ^ ((il&7)<<3))
template<int LEAF, int LAST>
__global__ __launch_bounds__(256, 2) void k_level(
    const unsigned short* __restrict__ embIn,
    const float* __restrict__ contO,   // [n][8] own contents
    const float* __restrict__ contC,   // [2n][8] child contents (LEAF only)
    const float* __restrict__ Wh,      // [128][384] f32
    const float* __restrict__ Wu,      // [128][8]
    const float* __restrict__ bu,      // [128]
    const float* __restrict__ bh,      // [128]
    unsigned short* __restrict__ embOut, // child-image layout
    float* __restrict__ outF,          // row-major f32 (LAST)
    int n_nodes)
{
    // LDS: 32K (A) + 16K (u) + 1K + 2K = 51 KiB
    __shared__ __align__(16) unsigned short A_lds[2][64][128]; // [cc][il][n^swz]
    __shared__ __align__(16) unsigned short u_lds[64][128];    // [i][n^swz]
    __shared__ __align__(16) unsigned short cpO[64][8];
    __shared__ __align__(16) unsigned short cpC[128][8];

    int t = threadIdx.x, lane = t & 63, wid = t >> 6;   // 4 waves, wid = col quarter
    int l15 = lane & 15, l4 = lane >> 4;

    // ---- persistent W fragments: n = wid*32 + nf2*16 + l15, k = kb*32 + l4*8 + e ----
    bf16x8 wreg[2][12];
    #pragma unroll
    for (int nf2 = 0; nf2 < 2; ++nf2) {
        int n = wid * 32 + nf2 * 16 + l15;
        #pragma unroll
        for (int kb = 0; kb < 12; ++kb) {
            const float* wp = Wh + n * 384 + kb * 32 + l4 * 8;
            f32x4 lo = *(const f32x4*)wp;
            f32x4 hi = *(const f32x4*)(wp + 4);
            bf16x8 v;
            #pragma unroll
            for (int e = 0; e < 4; ++e) {
                ((unsigned short*)&v)[e]     = f2bf(lo[e]);
                ((unsigned short*)&v)[e + 4] = f2bf(hi[e]);
            }
            wreg[nf2][kb] = v;
        }
    }
    // anti-rematerialization pin: values become opaque asm outputs
    #pragma unroll
    for (int kb = 0; kb < 12; ++kb)
        asm volatile("" : "+v"(wreg[0][kb]), "+v"(wreg[1][kb]));

    // ---- register Wu/bu fragments (B-op of the K=32-padded u-GEMM) ----
    bf16x8 wuf[8];
    #pragma unroll
    for (int nf = 0; nf < 8; ++nf) {
        bf16x8 v = {0, 0, 0, 0, 0, 0, 0, 0};
        int n = nf * 16 + l15;
        if (l4 == 0) {
            #pragma unroll
            for (int k = 0; k < 8; ++k) ((unsigned short*)&v)[k] = f2bf(Wu[n * 8 + k]);
        } else if (l4 == 1) {
            ((unsigned short*)&v)[0] = f2bf(bu[n]);   // bias column (k=8)
        }
        wuf[nf] = v;
    }
    #pragma unroll
    for (int nf = 0; nf < 8; ++nf)
        asm volatile("" : "+v"(wuf[nf]));

    float bhv[2];
    #pragma unroll
    for (int nf2 = 0; nf2 < 2; ++nf2) bhv[nf2] = bh[wid * 32 + nf2 * 16 + l15];

    bf16x8 onesA = {0, 0, 0, 0, 0, 0, 0, 0};
    ((unsigned short*)&onesA)[0] = 0x3F80;            // 1.0 at k=8
    const bf16x8 zeroA = {0, 0, 0, 0, 0, 0, 0, 0};

    int ntiles = n_nodes >> 6;
    for (int tile = blockIdx.x; tile < ntiles; tile += gridDim.x) {
        __syncthreads();  // (1) prev tile fully done (incl. epilogue LDS reads)

        if (!LEAF) {
            // A image: 2048 x 16B contiguous chunks, linear DMA (32 KiB)
            const unsigned short* src = embIn + (size_t)tile * 16384;
            #pragma unroll
            for (int it = 0; it < 8; ++it) {
                int q = t + it * 256;
                cp16_g2l(src + q * 8, &A_lds[0][0][0] + q * 8);
            }
        } else {
            // child contents: 128 rows x 8
            #pragma unroll
            for (int it = 0; it < 4; ++it) {
                int e = t + it * 256;
                cpC[e >> 3][e & 7] = f2bf(contC[(size_t)tile * 1024 + e]);
            }
        }
        // own contents: 64 rows x 8
        #pragma unroll
        for (int it = 0; it < 2; ++it) {
            int e = t + it * 256;
            cpO[e >> 3][e & 7] = f2bf(contO[(size_t)tile * 512 + e]);
        }

        // (2) barrier draining LDS writes but NOT the A DMA (vmcnt) -> DMA overlaps u-phase
        asm volatile("s_waitcnt lgkmcnt(0)" ::: "memory");
        __builtin_amdgcn_s_barrier();
        __builtin_amdgcn_sched_barrier(0);

        if (LEAF) {
            // child-u: wave computes child rows wid*32..+31, all 128 cols, into A image
            #pragma unroll
            for (int rb = 0; rb < 2; ++rb) {
                bf16x8 ac = (l4 == 0) ? *(const bf16x8*)&cpC[wid * 32 + rb * 16 + l15][0]
                          : (l4 == 1) ? onesA : zeroA;
                #pragma unroll
                for (int nf = 0; nf < 8; ++nf) {
                    f32x4 z = {0.f, 0.f, 0.f, 0.f};
                    z = __builtin_amdgcn_mfma_f32_16x16x32_bf16(ac, wuf[nf], z, 0, 0, 0);
                    #pragma unroll
                    for (int r = 0; r < 4; ++r) {
                        int rr = wid * 32 + rb * 16 + l4 * 4 + r;  // local child row
                        int cc = rr & 1, il = rr >> 1;
                        int n = nf * 16 + l15;
                        A_lds[cc][il][n ^ ((il & 7) << 3)] = f2bf(fmaxf(z[r], 0.f));
                    }
                }
            }
        }
        {
            // own-u: wave rows wid*16..+15, all 128 cols
            bf16x8 au = (l4 == 0) ? *(const bf16x8*)&cpO[wid * 16 + l15][0]
                      : (l4 == 1) ? onesA : zeroA;
            #pragma unroll
            for (int nf = 0; nf < 8; ++nf) {
                f32x4 z = {0.f, 0.f, 0.f, 0.f};
                z = __builtin_amdgcn_mfma_f32_16x16x32_bf16(au, wuf[nf], z, 0, 0, 0);
                #pragma unroll
                for (int r = 0; r < 4; ++r) {
                    int iu = wid * 16 + l4 * 4 + r;
                    int n = nf * 16 + l15;
                    u_lds[iu][n ^ ((iu & 7) << 3)] = f2bf(fmaxf(z[r], 0.f));
                }
            }
        }
        __syncthreads();  // (3) drains A DMA (vmcnt) + u/A LDS writes

        // ---- main GEMM: K=384 = [child0 | child1 | u], B entirely from registers ----
        f32x4 acc[4][2];
        #pragma unroll
        for (int mf = 0; mf < 4; ++mf)
            #pragma unroll
            for (int nf2 = 0; nf2 < 2; ++nf2)
                acc[mf][nf2] = (f32x4){bhv[nf2], bhv[nf2], bhv[nf2], bhv[nf2]};

        #pragma unroll
        for (int kb = 0; kb < 12; ++kb) {
            bf16x8 af[4];
            #pragma unroll
            for (int mf = 0; mf < 4; ++mf) {
                int i = mf * 16 + l15;
                const unsigned short* ap;
                if (kb < 8) ap = &A_lds[kb >> 2][i][((((kb & 3) * 4) + l4) ^ (i & 7)) * 8];
                else        ap = &u_lds[i][((((kb - 8) * 4) + l4) ^ (i & 7)) * 8];
                af[mf] = *(const bf16x8*)ap;
            }
            #pragma unroll
            for (int mf = 0; mf < 4; ++mf)
                #pragma unroll
                for (int nf2 = 0; nf2 < 2; ++nf2)
                    acc[mf][nf2] = __builtin_amdgcn_mfma_f32_16x16x32_bf16(af[mf], wreg[nf2][kb], acc[mf][nf2], 0, 0, 0);
        }

        // ---- epilogue ----
        if (LAST) {
            #pragma unroll
            for (int mf = 0; mf < 4; ++mf)
                #pragma unroll
                for (int nf2 = 0; nf2 < 2; ++nf2)
                    #pragma unroll
                    for (int r = 0; r < 4; ++r) {
                        int i = mf * 16 + l4 * 4 + r;
                        int n = wid * 32 + nf2 * 16 + l15;
                        outF[(size_t)(tile * 64 + i) * 128 + n] = fmaxf(acc[mf][nf2][r], 0.f);
                    }
        } else {
            // bounce through (dead) A_lds in image layout, then coalesced 16B stores
            __syncthreads();  // (4) all A/u reads done -> A_lds reusable
            unsigned short* ep = &A_lds[0][0][0];
            #pragma unroll
            for (int mf = 0; mf < 4; ++mf)
                #pragma unroll
                for (int nf2 = 0; nf2 < 2; ++nf2)
                    #pragma unroll
                    for (int r = 0; r < 4; ++r) {
                        int i = mf * 16 + l4 * 4 + r;
                        int n = wid * 32 + nf2 * 16 + l15;
                        // image pos for produced row Rg=tile*64+i: cc=i&1, il'=i>>1
                        int row = (i & 1) * 32 + (i >> 1);
                        ep[row * 128 + (n ^ (((i >> 1) & 7) << 3))] = f2bf(fmaxf(acc[mf][nf2][r], 0.f));
                    }
            __syncthreads();  // (5) ep writes visible
            size_t gbase = (size_t)(tile >> 1) * 16384 + (size_t)(tile & 1) * 4096;
            #pragma unroll
            for (int c = 0; c < 4; ++c) {
                int q = c * 256 + t;  // 16B chunk id, 1024 total
                bf16x8 v = *(const bf16x8*)&ep[q * 8];
                *reinterpret_cast<bf16x8*>(embOut + gbase + (size_t)(q >> 9) * 8192 + (q & 511) * 8) = v;
            }
        }
    }
}

extern "C" void kernel_launch(void* const* d_in, const int* in_sizes, int n_in,
                              void* d_out, int out_size, void* d_ws, size_t ws_size,
                              hipStream_t stream) {
    const float* contents[10];
    for (int j = 0; j < 10; ++j) contents[j] = (const float*)d_in[j];
    const float* Wu = (const float*)d_in[19];
    const float* bu = (const float*)d_in[20];
    const float* Wh = (const float*)d_in[21];
    const float* bh = (const float*)d_in[22];

    unsigned short* bufE = (unsigned short*)d_ws;                      // 64 MiB (even-level embs)
    unsigned short* bufO = (unsigned short*)((char*)d_ws + (64u << 20)); // 32 MiB (odd-level embs)

    // level 8 (leaf-fused): children = relu(contents_9 @ Wu^T + bu) computed in-kernel
    {
        int ntiles = (1024 << 8) >> 6;   // 4096
        int grid = ntiles < 512 ? ntiles : 512;
        k_level<1, 0><<<grid, 256, 0, stream>>>(nullptr, contents[8], contents[9], Wh,
                                                Wu, bu, bh, bufE, nullptr, 1024 << 8);
    }
    // levels 7..1
    for (int j = 7; j >= 1; --j) {
        int n = 1024 << j;
        const unsigned short* in = (j & 1) ? bufE : bufO;  // emb_{j+1}
        unsigned short* outp     = (j & 1) ? bufO : bufE;  // emb_j
        int ntiles = n >> 6;
        int grid = ntiles < 512 ? ntiles : 512;
        k_level<0, 0><<<grid, 256, 0, stream>>>(in, contents[j], nullptr, Wh,
                                                Wu, bu, bh, outp, nullptr, n);
    }
    // level 0 -> f32 output (16 tiles)
    k_level<0, 1><<<16, 256, 0, stream>>>(bufO, contents[0], nullptr, Wh,
                                          Wu, bu, bh, nullptr, (float*)d_out, 1024);
}

// Round 6
// 251.365 us; speedup vs baseline: 1.7139x; 1.0094x over previous
//
#include <hip/hip_runtime.h>

typedef __attribute__((ext_vector_type(8))) short bf16x8;
typedef __attribute__((ext_vector_type(4))) float f32x4;

__device__ __forceinline__ unsigned short f2bf(float f) {
    union { float f; unsigned int u; } v; v.f = f;
    unsigned int u = v.u;
    return (unsigned short)((u + 0x7FFFu + ((u >> 16) & 1u)) >> 16);
}

__device__ __forceinline__ void cp16_g2l(const void* g, void* l) {
    __builtin_amdgcn_global_load_lds(
        (const __attribute__((address_space(1))) unsigned int*)g,
        (__attribute__((address_space(3))) unsigned int*)l, 16, 0, 0);
}

// Block tile: 64 own rows x 128 cols, 4 waves (wave = 64 rows x 32-col quarter).
// W_h in registers (pinned). Wu/bu fragment table in LDS. Contents prefetched
// one tile ahead straight into the u-MFMA A-fragment lanes. A-tile DMA
// prefetched one tile ahead, drained by counted vmcnt(4) at the phase barrier.
template<int LEAF, int LAST>
__global__ __launch_bounds__(256, 2) void k_level(
    const unsigned short* __restrict__ embIn,
    const float* __restrict__ contO,   // [n][8] own contents
    const float* __restrict__ contC,   // [2n][8] child contents (LEAF only)
    const float* __restrict__ Wh,      // [128][384] f32
    const float* __restrict__ Wu,      // [128][8]
    const float* __restrict__ bu,      // [128]
    const float* __restrict__ bh,      // [128]
    unsigned short* __restrict__ embOut, // child-image layout
    float* __restrict__ outF,          // row-major f32 (LAST)
    int n_nodes)
{
    // LDS: 32K (A) + 16K (u) + 4K (wu) = 52 KiB -> 3 blocks/CU
    __shared__ __align__(16) unsigned short A_lds[2][64][128]; // [cc][il][n^swz]
    __shared__ __align__(16) unsigned short u_lds[64][128];    // [i][n^swz] (+ epilogue bounce)
    __shared__ __align__(16) unsigned short wu_lds[8][32][8];  // [nf][l4*16+l15][e]

    const int t = threadIdx.x, lane = t & 63, wid = t >> 6;
    const int l15 = lane & 15, l4 = lane >> 4;

    // ---- persistent W fragments: n = wid*32 + nf2*16 + l15, k = kb*32 + l4*8 + e ----
    bf16x8 wreg[2][12];
    #pragma unroll
    for (int nf2 = 0; nf2 < 2; ++nf2) {
        int n = wid * 32 + nf2 * 16 + l15;
        #pragma unroll
        for (int kb = 0; kb < 12; ++kb) {
            const float* wp = Wh + n * 384 + kb * 32 + l4 * 8;
            f32x4 lo = *(const f32x4*)wp;
            f32x4 hi = *(const f32x4*)(wp + 4);
            bf16x8 v;
            #pragma unroll
            for (int e = 0; e < 4; ++e) {
                ((unsigned short*)&v)[e]     = f2bf(lo[e]);
                ((unsigned short*)&v)[e + 4] = f2bf(hi[e]);
            }
            wreg[nf2][kb] = v;
        }
    }
    #pragma unroll
    for (int kb = 0; kb < 12; ++kb)
        asm volatile("" : "+v"(wreg[0][kb]), "+v"(wreg[1][kb]));

    // ---- Wu/bu fragment table (B-op of K=32-padded u-GEMM), written by wave 0 ----
    if (wid == 0 && l4 < 2) {
        #pragma unroll
        for (int nf = 0; nf < 8; ++nf) {
            int n = nf * 16 + l15;
            bf16x8 v = {0, 0, 0, 0, 0, 0, 0, 0};
            if (l4 == 0) {
                #pragma unroll
                for (int k = 0; k < 8; ++k) ((unsigned short*)&v)[k] = f2bf(Wu[n * 8 + k]);
            } else {
                ((unsigned short*)&v)[0] = f2bf(bu[n]);   // bias column (k=8)
            }
            *(bf16x8*)&wu_lds[nf][l4 * 16 + l15][0] = v;
        }
    }
    const float bhv0 = bh[wid * 32 + l15];
    const float bhv1 = bh[wid * 32 + 16 + l15];

    bf16x8 zeroA = {0, 0, 0, 0, 0, 0, 0, 0};
    bf16x8 onesA = zeroA; ((unsigned short*)&onesA)[0] = 0x3F80;  // 1.0 at k=8

    const int ntiles = n_nodes >> 6;
    const int stride = gridDim.x;
    const int tile0 = blockIdx.x;
    if (tile0 >= ntiles) return;

    // ---- contents prefetch registers (A-fragment lanes: l4==0 holds the row) ----
    f32x4 cO0 = {0,0,0,0}, cO1 = {0,0,0,0};
    f32x4 cC00 = {0,0,0,0}, cC01 = {0,0,0,0}, cC10 = {0,0,0,0}, cC11 = {0,0,0,0};

    // ---- prologue: tile0 A DMA + contents ----
    if (!LEAF) {
        const unsigned short* src = embIn + (size_t)tile0 * 16384;
        #pragma unroll
        for (int it = 0; it < 8; ++it) {
            int q = t + it * 256;
            cp16_g2l(src + q * 8, &A_lds[0][0][0] + q * 8);
        }
    }
    if (l4 == 0) {
        const float* p = contO + ((size_t)tile0 * 64 + wid * 16 + l15) * 8;
        cO0 = *(const f32x4*)p; cO1 = *(const f32x4*)(p + 4);
        if (LEAF) {
            const float* pc = contC + ((size_t)tile0 * 128 + wid * 32 + l15) * 8;
            cC00 = *(const f32x4*)pc;         cC01 = *(const f32x4*)(pc + 4);
            cC10 = *(const f32x4*)(pc + 128); cC11 = *(const f32x4*)(pc + 132);
        }
    }
    __syncthreads();  // drains prologue DMA/loads + wu_lds visible

    for (int tile = tile0; tile < ntiles; tile += stride) {
        const int tnext = tile + stride;

        // ======== u-phase: from regs, no LDS staging ========
        {
            bf16x8 au = zeroA;
            if (l4 == 0) {
                #pragma unroll
                for (int e = 0; e < 4; ++e) {
                    ((unsigned short*)&au)[e]     = f2bf(cO0[e]);
                    ((unsigned short*)&au)[e + 4] = f2bf(cO1[e]);
                }
            } else if (l4 == 1) au = onesA;
            #pragma unroll
            for (int nf = 0; nf < 8; ++nf) {
                bf16x8 wv = zeroA;
                if (l4 < 2) wv = *(const bf16x8*)&wu_lds[nf][l4 * 16 + l15][0];
                f32x4 z = {0.f, 0.f, 0.f, 0.f};
                z = __builtin_amdgcn_mfma_f32_16x16x32_bf16(au, wv, z, 0, 0, 0);
                #pragma unroll
                for (int r = 0; r < 4; ++r) {
                    int iu = wid * 16 + l4 * 4 + r;
                    int n = nf * 16 + l15;
                    u_lds[iu][n ^ ((iu & 7) << 3)] = f2bf(fmaxf(z[r], 0.f));
                }
            }
        }
        if (LEAF) {
            #pragma unroll
            for (int rb = 0; rb < 2; ++rb) {
                bf16x8 ac = zeroA;
                if (l4 == 0) {
                    f32x4 a = rb ? cC10 : cC00, b = rb ? cC11 : cC01;
                    #pragma unroll
                    for (int e = 0; e < 4; ++e) {
                        ((unsigned short*)&ac)[e]     = f2bf(a[e]);
                        ((unsigned short*)&ac)[e + 4] = f2bf(b[e]);
                    }
                } else if (l4 == 1) ac = onesA;
                #pragma unroll
                for (int nf = 0; nf < 8; ++nf) {
                    bf16x8 wv = zeroA;
                    if (l4 < 2) wv = *(const bf16x8*)&wu_lds[nf][l4 * 16 + l15][0];
                    f32x4 z = {0.f, 0.f, 0.f, 0.f};
                    z = __builtin_amdgcn_mfma_f32_16x16x32_bf16(ac, wv, z, 0, 0, 0);
                    #pragma unroll
                    for (int r = 0; r < 4; ++r) {
                        int rr = wid * 32 + rb * 16 + l4 * 4 + r;  // local child row
                        int cc = rr & 1, il = rr >> 1;
                        int n = nf * 16 + l15;
                        A_lds[cc][il][n ^ ((il & 7) << 3)] = f2bf(fmaxf(z[r], 0.f));
                    }
                }
            }
        }

        // ---- prefetch next tile's contents (issue-early, consumed next iter) ----
        if (tnext < ntiles && l4 == 0) {
            const float* p = contO + ((size_t)tnext * 64 + wid * 16 + l15) * 8;
            cO0 = *(const f32x4*)p; cO1 = *(const f32x4*)(p + 4);
            if (LEAF) {
                const float* pc = contC + ((size_t)tnext * 128 + wid * 32 + l15) * 8;
                cC00 = *(const f32x4*)pc;         cC01 = *(const f32x4*)(pc + 4);
                cC10 = *(const f32x4*)(pc + 128); cC11 = *(const f32x4*)(pc + 132);
            }
        }

        // ======== phase barrier: A slabs ready (counted vmcnt), u/A visible ========
        if (!LEAF) asm volatile("s_waitcnt vmcnt(4)" ::: "memory");  // drains prev-issued DMA; leaves stores
        asm volatile("s_waitcnt lgkmcnt(0)" ::: "memory");
        __builtin_amdgcn_sched_barrier(0);
        __builtin_amdgcn_s_barrier();
        __builtin_amdgcn_sched_barrier(0);

        // ======== main GEMM: K=384 = [child0 | child1 | u] ========
        f32x4 acc[4][2];
        #pragma unroll
        for (int mf = 0; mf < 4; ++mf) {
            acc[mf][0] = (f32x4){bhv0, bhv0, bhv0, bhv0};
            acc[mf][1] = (f32x4){bhv1, bhv1, bhv1, bhv1};
        }

        #pragma unroll
        for (int kb = 0; kb < 8; ++kb) {   // A slabs
            bf16x8 af[4];
            #pragma unroll
            for (int mf = 0; mf < 4; ++mf) {
                int i = mf * 16 + l15;
                af[mf] = *(const bf16x8*)&A_lds[kb >> 2][i][((((kb & 3) * 4) + l4) ^ (i & 7)) * 8];
            }
            #pragma unroll
            for (int mf = 0; mf < 4; ++mf) {
                acc[mf][0] = __builtin_amdgcn_mfma_f32_16x16x32_bf16(af[mf], wreg[0][kb], acc[mf][0], 0, 0, 0);
                acc[mf][1] = __builtin_amdgcn_mfma_f32_16x16x32_bf16(af[mf], wreg[1][kb], acc[mf][1], 0, 0, 0);
            }
        }

        // A fully consumed -> barrier, then prefetch next tile's A DMA
        if (!LEAF) {
            asm volatile("s_waitcnt lgkmcnt(0)" ::: "memory");
            __builtin_amdgcn_sched_barrier(0);
            __builtin_amdgcn_s_barrier();
            __builtin_amdgcn_sched_barrier(0);
            if (tnext < ntiles) {
                const unsigned short* src = embIn + (size_t)tnext * 16384;
                #pragma unroll
                for (int it = 0; it < 8; ++it) {
                    int q = t + it * 256;
                    cp16_g2l(src + q * 8, &A_lds[0][0][0] + q * 8);
                }
            }
        }

        #pragma unroll
        for (int kb = 8; kb < 12; ++kb) {  // u
            bf16x8 af[4];
            #pragma unroll
            for (int mf = 0; mf < 4; ++mf) {
                int i = mf * 16 + l15;
                af[mf] = *(const bf16x8*)&u_lds[i][((((kb - 8) * 4) + l4) ^ (i & 7)) * 8];
            }
            #pragma unroll
            for (int mf = 0; mf < 4; ++mf) {
                acc[mf][0] = __builtin_amdgcn_mfma_f32_16x16x32_bf16(af[mf], wreg[0][kb], acc[mf][0], 0, 0, 0);
                acc[mf][1] = __builtin_amdgcn_mfma_f32_16x16x32_bf16(af[mf], wreg[1][kb], acc[mf][1], 0, 0, 0);
            }
        }

        // ======== epilogue ========
        if (LAST) {
            #pragma unroll
            for (int mf = 0; mf < 4; ++mf)
                #pragma unroll
                for (int nf2 = 0; nf2 < 2; ++nf2)
                    #pragma unroll
                    for (int r = 0; r < 4; ++r) {
                        int i = mf * 16 + l4 * 4 + r;
                        int n = wid * 32 + nf2 * 16 + l15;
                        outF[(size_t)(tile * 64 + i) * 128 + n] = fmaxf(acc[mf][nf2][r], 0.f);
                    }
        } else {
            // u_lds reads (kb8-11) done by all waves before reuse as bounce buffer
            asm volatile("s_waitcnt lgkmcnt(0)" ::: "memory");
            __builtin_amdgcn_sched_barrier(0);
            __builtin_amdgcn_s_barrier();        // [A]
            unsigned short* ep = &u_lds[0][0];
            #pragma unroll
            for (int mf = 0; mf < 4; ++mf)
                #pragma unroll
                for (int nf2 = 0; nf2 < 2; ++nf2)
                    #pragma unroll
                    for (int r = 0; r < 4; ++r) {
                        int i = mf * 16 + l4 * 4 + r;
                        int n = wid * 32 + nf2 * 16 + l15;
                        int row = (i & 1) * 32 + (i >> 1);   // image row within tile
                        ep[row * 128 + (n ^ (((i >> 1) & 7) << 3))] = f2bf(fmaxf(acc[mf][nf2][r], 0.f));
                    }
            asm volatile("s_waitcnt lgkmcnt(0)" ::: "memory");
            __builtin_amdgcn_s_barrier();        // [B] ep writes visible
            bf16x8 ev0 = *(const bf16x8*)&ep[(0 * 256 + t) * 8];
            bf16x8 ev1 = *(const bf16x8*)&ep[(1 * 256 + t) * 8];
            bf16x8 ev2 = *(const bf16x8*)&ep[(2 * 256 + t) * 8];
            bf16x8 ev3 = *(const bf16x8*)&ep[(3 * 256 + t) * 8];
            asm volatile("s_waitcnt lgkmcnt(0)" ::: "memory");
            __builtin_amdgcn_sched_barrier(0);
            __builtin_amdgcn_s_barrier();        // [C] reads done -> u_lds free next iter
            size_t gbase = (size_t)(tile >> 1) * 16384 + (size_t)(tile & 1) * 4096;
            unsigned short* gp = embOut + gbase;
            *(bf16x8*)(gp + (size_t)((0 * 256 + t) >> 9) * 8192 + ((0 * 256 + t) & 511) * 8) = ev0;
            *(bf16x8*)(gp + (size_t)((1 * 256 + t) >> 9) * 8192 + ((1 * 256 + t) & 511) * 8) = ev1;
            *(bf16x8*)(gp + (size_t)((2 * 256 + t) >> 9) * 8192 + ((2 * 256 + t) & 511) * 8) = ev2;
            *(bf16x8*)(gp + (size_t)((3 * 256 + t) >> 9) * 8192 + ((3 * 256 + t) & 511) * 8) = ev3;
        }
    }
}

extern "C" void kernel_launch(void* const* d_in, const int* in_sizes, int n_in,
                              void* d_out, int out_size, void* d_ws, size_t ws_size,
                              hipStream_t stream) {
    const float* contents[10];
    for (int j = 0; j < 10; ++j) contents[j] = (const float*)d_in[j];
    const float* Wu = (const float*)d_in[19];
    const float* bu = (const float*)d_in[20];
    const float* Wh = (const float*)d_in[21];
    const float* bh = (const float*)d_in[22];

    unsigned short* bufE = (unsigned short*)d_ws;                        // 64 MiB (even-level embs)
    unsigned short* bufO = (unsigned short*)((char*)d_ws + (64u << 20)); // 32 MiB (odd-level embs)

    // level 8 (leaf-fused): children = relu(contents_9 @ Wu^T + bu) computed in-kernel
    {
        int ntiles = (1024 << 8) >> 6;   // 4096
        int grid = ntiles < 768 ? ntiles : 768;
        k_level<1, 0><<<grid, 256, 0, stream>>>(nullptr, contents[8], contents[9], Wh,
                                                Wu, bu, bh, bufE, nullptr, 1024 << 8);
    }
    // levels 7..1
    for (int j = 7; j >= 1; --j) {
        int n = 1024 << j;
        const unsigned short* in = (j & 1) ? bufE : bufO;  // emb_{j+1}
        unsigned short* outp     = (j & 1) ? bufO : bufE;  // emb_j
        int ntiles = n >> 6;
        int grid = ntiles < 768 ? ntiles : 768;
        k_level<0, 0><<<grid, 256, 0, stream>>>(in, contents[j], nullptr, Wh,
                                                Wu, bu, bh, outp, nullptr, n);
    }
    // level 0 -> f32 output (16 tiles)
    k_level<0, 1><<<16, 256, 0, stream>>>(bufO, contents[0], nullptr, Wh,
                                          Wu, bu, bh, nullptr, (float*)d_out, 1024);
}